// Round 6
// baseline (214.889 us; speedup 1.0000x reference)
//
#include <hip/hip_runtime.h>

#define C_IN   672
#define C_OUT  128
#define HW     49
#define XELEMS (C_IN*HW)      // 32928
#define BK     32             // K-chunk = 1 MFMA k-step (fine-grained)
#define NCH    21             // 672/32
#define CHUNK  (BK*HW)        // 1568 floats per chunk
#define RS2    40             // hT row stride in halfs (80 B: 16B-aligned rows, 2-way banks)
#define NROWS  64             // padded N (s) dimension
#define SSPAD  680            // s_ss entries: 672 + pad for speculative c0+1 read
#define DEPTH  5              // prefetch depth (both x and W streams)

typedef short  short8  __attribute__((ext_vector_type(8)));
typedef float  f4      __attribute__((ext_vector_type(4)));
typedef float  f2      __attribute__((ext_vector_type(2)));

template<int N> struct IC { static constexpr int v = N; };

__device__ __forceinline__ void waitlgkm0() {
    asm volatile("s_waitcnt lgkmcnt(0)" ::: "memory");
}

__device__ __forceinline__ unsigned short f2bf(float f) {
    unsigned u = __float_as_uint(f);
    u += 0x7fffu + ((u >> 16) & 1u);
    return (unsigned short)(u >> 16);
}

__global__ __launch_bounds__(256) void prep_kernel(
        const float* __restrict__ gamma,
        const float* __restrict__ beta,
        const float* __restrict__ rmean,
        const float* __restrict__ rvar,
        const float* __restrict__ W,
        unsigned short* __restrict__ Wbf,
        float* __restrict__ scale,
        float* __restrict__ shift) {
    int i = blockIdx.x * 256 + threadIdx.x;
    if (i < C_IN) {
        float inv = rsqrtf(rvar[i] + 1e-5f);
        float sc  = gamma[i] * inv;
        scale[i] = sc;
        shift[i] = beta[i] - rmean[i] * sc;
    }
    if (i < C_OUT * C_IN) Wbf[i] = f2bf(W[i]);
}

// out_b(128x49) = W(128x672) @ relu(x_b*scale+shift)(672x49), one block per b.
// R11: fine-grained equal-depth pipeline. R5/R7/R8/R10 (four different
// schedules) all pinned at gemm ~76-85us: shared traits were (1) coarse
// 19KB step quanta, (2) UNEQUAL vmem stream depth -- av issued ~1 step
// before use, and in-order vmcnt retirement means waiting av also demands
// the younger-lead x chunks landed, collapsing effective lead, (3) 8-wave
// barrier convoys with 2 phase-locked blocks/CU -> bursty issue, queues
// drain, avg in-flight bytes collapse (1.2 TB/s observed).
// Now: BK=32 -> 21 fine steps (6.3KB quanta); BOTH streams (x pieces and
// W-frags) issued DEPTH=5 steps ahead at the END of each step, so every
// in-order wait finds its operand >=4 steps (~1200cy) old; 4-wave blocks,
// M=32/wave, 12 waves/CU = 3 independent block-pipelines per CU. All
// staging in named SSA slots (R9 scratch lesson); acc/bv arrays are
// constant-indexed only. Raw s_barrier + lgkmcnt(0); vmem never drained.
__global__ __launch_bounds__(256, 3) void gemm_kernel(
        const float* __restrict__ x,
        const unsigned short* __restrict__ Wbf,
        const float* __restrict__ scale,
        const float* __restrict__ shift,
        float* __restrict__ out) {
    __shared__ f2 s_ss[SSPAD];                       // (scale,shift) interleaved
    __shared__ unsigned short hT[2][NROWS * RS2];    // 2 x 5.1 KB double buffer

    const int tid  = threadIdx.x;
    const int wv   = tid >> 6;          // 0..3, owns out rows wv*32..+31
    const int lane = tid & 63;
    const int quad = lane >> 4;
    const int l16  = lane & 15;
    const float* xb = x + (size_t)blockIdx.x * XELEMS;

    // zero both hT buffers once: pad rows 49..63 stay clean zeros
    for (int i = tid; i < (2 * NROWS * RS2) / 4; i += 256)
        ((unsigned long long*)hT)[i] = 0ull;
    // stage (scale,shift); these global loads + ds_writes complete BEFORE any
    // x/W issue (program order), so their waits never touch the pipeline.
    for (int i = tid; i < C_IN; i += 256)
        s_ss[i] = (f2){scale[i], shift[i]};
    if (tid < SSPAD - C_IN) s_ss[C_IN + tid] = (f2){0.f, 0.f};

    // ---- named SSA slots: never address-taken ----
    f4 xa0, xc0, xa1, xc1, xa2, xc2, xa3, xc3, xa4, xc4;     // x: 5 slots x 2 f4
    short8 a00, a10, a01, a11, a02, a12, a03, a13, a04, a14; // av: 5 slots x 2 m-tiles

    auto issue_x = [&](auto sc, int kc) {
        constexpr int S = decltype(sc)::v;
        const float* src = xb + kc * CHUNK;
        int t1 = 1024 + tid * 4;
        if (t1 > CHUNK - 4) t1 = CHUNK - 4;          // clamp; extras masked in transform
        f4 a = *(const f4*)(src + tid * 4);
        f4 c = *(const f4*)(src + t1);
        if constexpr (S == 0) { xa0 = a; xc0 = c; }
        else if constexpr (S == 1) { xa1 = a; xc1 = c; }
        else if constexpr (S == 2) { xa2 = a; xc2 = c; }
        else if constexpr (S == 3) { xa3 = a; xc3 = c; }
        else                       { xa4 = a; xc4 = c; }
    };
    auto issue_av = [&](auto sc, int kc) {
        constexpr int S = decltype(sc)::v;
        int row0 = wv * 32 + l16;
        const unsigned short* wp = Wbf + row0 * C_IN + kc * BK + quad * 8;
        short8 m0 = *(const short8*)(wp);
        short8 m1 = *(const short8*)(wp + 16 * C_IN);
        if constexpr (S == 0) { a00 = m0; a10 = m1; }
        else if constexpr (S == 1) { a01 = m0; a11 = m1; }
        else if constexpr (S == 2) { a02 = m0; a12 = m1; }
        else if constexpr (S == 3) { a03 = m0; a13 = m1; }
        else                       { a04 = m0; a14 = m1; }
    };
    auto xga = [&](auto sc) -> f4 {
        constexpr int S = decltype(sc)::v;
        if constexpr (S == 0) return xa0; else if constexpr (S == 1) return xa1;
        else if constexpr (S == 2) return xa2; else if constexpr (S == 3) return xa3;
        else return xa4;
    };
    auto xgc = [&](auto sc) -> f4 {
        constexpr int S = decltype(sc)::v;
        if constexpr (S == 0) return xc0; else if constexpr (S == 1) return xc1;
        else if constexpr (S == 2) return xc2; else if constexpr (S == 3) return xc3;
        else return xc4;
    };
    auto ag0 = [&](auto sc) -> short8 {
        constexpr int S = decltype(sc)::v;
        if constexpr (S == 0) return a00; else if constexpr (S == 1) return a01;
        else if constexpr (S == 2) return a02; else if constexpr (S == 3) return a03;
        else return a04;
    };
    auto ag1 = [&](auto sc) -> short8 {
        constexpr int S = decltype(sc)::v;
        if constexpr (S == 0) return a10; else if constexpr (S == 1) return a11;
        else if constexpr (S == 2) return a12; else if constexpr (S == 3) return a13;
        else return a14;
    };

    // BN+ReLU+bf16 in register -> transposed scatter into hT[buf].
    auto xf4 = [&](f4 xv, int vb, int kc, unsigned short* h, bool tail) {
        int cb = vb;
        if (tail && cb > CHUNK - 4) cb = CHUNK - 4;  // matches issue_x clamp
        int c0 = cb / HW;                            // magic-div by 49
        int s0 = cb - c0 * HW;
        f2 p0 = s_ss[kc * BK + c0];
        f2 p1 = s_ss[kc * BK + c0 + 1];              // c0+1<=32: SSPAD covers kc=20 edge
        #pragma unroll
        for (int jj = 0; jj < 4; ++jj) {
            int s = s0 + jj, c = c0;
            f2 pp = p0;
            if (s >= HW) { s -= HW; c = c0 + 1; pp = p1; }  // crosses <=1 boundary
            float v = fmaxf(xv[jj] * pp.x + pp.y, 0.f);
            if (!tail || vb + jj < CHUNK)
                h[s * RS2 + c] = f2bf(v);
        }
    };
    auto transform = [&](f4 va, f4 vc, int kc, int buf) {
        unsigned short* h = &hT[buf][0];
        xf4(va, tid * 4, kc, h, false);              // covers idx 0..1023
        xf4(vc, 1024 + tid * 4, kc, h, true);        // covers 1024..1567, clamped tail
    };

    f4 acc0[4], acc1[4];
    #pragma unroll
    for (int nt = 0; nt < 4; ++nt) {
        acc0[nt] = (f4){0.f, 0.f, 0.f, 0.f};
        acc1[nt] = (f4){0.f, 0.f, 0.f, 0.f};
    }

    auto mfma_phase = [&](short8 m0, short8 m1, int buf) {
        const unsigned short* h = &hT[buf][0];
        short8 bv[4];
        #pragma unroll
        for (int nt = 0; nt < 4; ++nt)               // one ds_read_b128 each, rows 16B-aligned
            bv[nt] = *(const short8*)(h + (nt * 16 + l16) * RS2 + quad * 8);
        #pragma unroll
        for (int nt = 0; nt < 4; ++nt)
            acc0[nt] = __builtin_amdgcn_mfma_f32_16x16x32_bf16(m0, bv[nt], acc0[nt], 0, 0, 0);
        #pragma unroll
        for (int nt = 0; nt < 4; ++nt)
            acc1[nt] = __builtin_amdgcn_mfma_f32_16x16x32_bf16(m1, bv[nt], acc1[nt], 0, 0, 0);
    };

    // prologue: 5 batches of (x, av) in flight (20 vmem insts/wave < 63 cap)
    issue_x(IC<0>{}, 0); issue_av(IC<0>{}, 0);
    issue_x(IC<1>{}, 1); issue_av(IC<1>{}, 1);
    issue_x(IC<2>{}, 2); issue_av(IC<2>{}, 2);
    issue_x(IC<3>{}, 3); issue_av(IC<3>{}, 3);
    issue_x(IC<4>{}, 4); issue_av(IC<4>{}, 4);
    waitlgkm0();
    __builtin_amdgcn_s_barrier();       // hT zeros + s_ss visible; vmem stays in flight
    transform(xga(IC<0>{}), xgc(IC<0>{}), 0, 0);   // waits x(0) only (batches 1..4 younger)
    waitlgkm0();
    __builtin_amdgcn_s_barrier();       // hT[0] ready

    // step KC: MFMA(KC) from hT[KC&1] (waits av(KC), issued >=4 steps ago) ||
    // transform(KC+1) -> hT[~] (waits x(KC+1), same batch as av(KC) -> already
    // retired) || issue batch KC+5 into slot KC%5 (freed this step). One
    // lgkm0+barrier per step; WAR on hT[(KC+1)&1] covered by barrier(KC-1).
    auto step = [&](auto kcc) {
        constexpr int KC = decltype(kcc)::v;
        constexpr int SL = KC % DEPTH;
        mfma_phase(ag0(IC<SL>{}), ag1(IC<SL>{}), KC & 1);
        if constexpr (KC < NCH - 1)
            transform(xga(IC<(KC + 1) % DEPTH>{}), xgc(IC<(KC + 1) % DEPTH>{}),
                      KC + 1, (KC + 1) & 1);
        if constexpr (KC + DEPTH <= NCH - 1) {
            issue_x(IC<SL>{}, KC + DEPTH);
            issue_av(IC<SL>{}, KC + DEPTH);
        }
        if constexpr (KC < NCH - 1) {
            waitlgkm0();
            __builtin_amdgcn_s_barrier();
        }
    };
    step(IC<0>{});  step(IC<1>{});  step(IC<2>{});  step(IC<3>{});  step(IC<4>{});
    step(IC<5>{});  step(IC<6>{});  step(IC<7>{});  step(IC<8>{});  step(IC<9>{});
    step(IC<10>{}); step(IC<11>{}); step(IC<12>{}); step(IC<13>{}); step(IC<14>{});
    step(IC<15>{}); step(IC<16>{}); step(IC<17>{}); step(IC<18>{}); step(IC<19>{});
    step(IC<20>{});

    // epilogue: C/D layout col=lane&15, row=quad*4+reg (m89-verified); mask s>=49
    float* outb = out + (size_t)blockIdx.x * (C_OUT * HW);
    #pragma unroll
    for (int nt = 0; nt < 4; ++nt) {
        int scol = nt * 16 + l16;
        if (scol < HW) {
            #pragma unroll
            for (int i = 0; i < 4; ++i) {
                int o0 = wv * 32 + quad * 4 + i;
                outb[o0 * HW + scol] = acc0[nt][i];
                outb[(o0 + 16) * HW + scol] = acc1[nt][i];
            }
        }
    }
}

extern "C" void kernel_launch(void* const* d_in, const int* in_sizes, int n_in,
                              void* d_out, int out_size, void* d_ws, size_t ws_size,
                              hipStream_t stream) {
    const float* x     = (const float*)d_in[0];
    const float* gamma = (const float*)d_in[1];
    const float* beta  = (const float*)d_in[2];
    const float* rmean = (const float*)d_in[3];
    const float* rvar  = (const float*)d_in[4];
    const float* W     = (const float*)d_in[5];
    float* out = (float*)d_out;

    // ws layout: [bf16 W: 86016*2 B][scale: 672 f32][shift: 672 f32]  (~173 KB)
    unsigned short* Wbf = (unsigned short*)d_ws;
    float* scale = (float*)((char*)d_ws + (size_t)C_OUT * C_IN * 2);
    float* shift = scale + C_IN;

    prep_kernel<<<(C_OUT * C_IN + 255) / 256, 256, 0, stream>>>(
        gamma, beta, rmean, rvar, W, Wbf, scale, shift);
    gemm_kernel<<<1024, 256, 0, stream>>>(x, Wbf, scale, shift, out);
}